// Round 8
// baseline (364.429 us; speedup 1.0000x reference)
//
#include <hip/hip_runtime.h>
#include <hip/hip_cooperative_groups.h>
#include <math.h>

namespace cg = cooperative_groups;

#define T_SEQ 2048
#define D_MODEL 1024
#define DH 128
#define SLOTS 288          // per batch: sum_{qt=0..63} ((qt>>3)+1)
#define FRAG_B 262144      // frag-plane elems per batch: 128*4*512 (= 64*8*512)

typedef __bf16 bfx8 __attribute__((ext_vector_type(8)));
typedef float f32x4 __attribute__((ext_vector_type(4)));

union U16x8 { uint4 u4; unsigned int ui[4]; unsigned short us[8]; __bf16 bf[8]; bfx8 v; };

__device__ inline uint4 cvt8u(float4 a, float4 b) {
    U16x8 u;
    u.bf[0] = (__bf16)a.x; u.bf[1] = (__bf16)a.y; u.bf[2] = (__bf16)a.z; u.bf[3] = (__bf16)a.w;
    u.bf[4] = (__bf16)b.x; u.bf[5] = (__bf16)b.y; u.bf[6] = (__bf16)b.z; u.bf[7] = (__bf16)b.w;
    return u.u4;
}

__device__ inline int slot_base32(int qt) {   // sum_{i<qt} ((i>>3)+1)
    int g = qt >> 3, j = qt & 7;
    return 4 * g * (g + 1) + j * (g + 1);
}

// ============================================================================
// FALLBACK PATH — byte-identical round-6 kernels (proven, 122.4 us).
// Deliberately does NOT share device code with the fused kernel.
// ============================================================================

__global__ __launch_bounds__(256) void prep_kernel(
    const float* __restrict__ x,
    const float* __restrict__ Wq, const float* __restrict__ Wk,
    const float* __restrict__ Wv,
    __bf16* __restrict__ xF, __bf16* __restrict__ WF, int nxb)
{
    const int bi = blockIdx.x;
    const int tid = threadIdx.x;

    if (bi < nxb) {
        __shared__ __align__(16) unsigned short Xs[64 * 72];   // 9 KB
        const int m0 = (bi >> 4) * 64;
        const int k0 = (bi & 15) * 64;
        const int row = tid >> 2, cs = (tid & 3) * 16;
        const float* xp = x + (size_t)(m0 + row) * D_MODEL + k0 + cs;
        float4 a0 = *(const float4*)xp;
        float4 a1 = *(const float4*)(xp + 4);
        float4 a2 = *(const float4*)(xp + 8);
        float4 a3 = *(const float4*)(xp + 12);
        *(uint4*)&Xs[row * 72 + cs]     = cvt8u(a0, a1);
        *(uint4*)&Xs[row * 72 + cs + 8] = cvt8u(a2, a3);
        __syncthreads();
        const int L = tid & 63;
        #pragma unroll
        for (int rr = 0; rr < 2; ++rr) {
            const int fid = rr * 4 + (tid >> 6);
            const int mtl = fid >> 1, kcl = fid & 1;
            uint4 d = *(const uint4*)&Xs[(mtl * 16 + (L & 15)) * 72 + kcl * 32 + (L >> 4) * 8];
            const size_t frag = (size_t)((m0 >> 4) + mtl) * 32 + (k0 >> 5) + kcl;
            *(uint4*)&xF[frag * 512 + L * 8] = d;
        }
    } else {
        const int i = (bi - nxb) * 256 + tid;
        const int wsel = i >> 14;
        const int i2 = i & 16383;
        const int kc = i2 >> 9, j = (i2 >> 6) & 7, ln = i2 & 63;
        const int lo = ln & 15, quad = ln >> 4;
        const float* src = (wsel == 0) ? Wq : (wsel == 1) ? Wk : Wv;
        const float* p = src + (size_t)(j * 16 + lo) * D_MODEL + kc * 32 + quad * 8;
        float4 a = *(const float4*)p;
        float4 b = *(const float4*)(p + 4);
        *(uint4*)&WF[(size_t)((wsel * 32 + kc) * 8 + j) * 512 + ln * 8] = cvt8u(a, b);
    }
}

__global__ __launch_bounds__(64) void qkv_kernel(
    const __bf16* __restrict__ xF, const __bf16* __restrict__ WF,
    const float* __restrict__ theta,
    __bf16* __restrict__ QF, __bf16* __restrict__ KF, __bf16* __restrict__ VF)
{
    __shared__ __align__(16) unsigned short T[32 * 136];

    const int bx = blockIdx.x;
    const int ln = threadIdx.x;
    const int lo = ln & 15, quad = ln >> 4;

    if (bx < 2048) {
        const int wsel01 = bx >> 10;
        const int sub = (bx >> 8) & 3;
        const int iq = sub >> 1, jh = sub & 1;
        const int mt = bx & 255;
        const int mt16 = mt * 2 + iq;

        const __bf16* WFp = WF + (size_t)wsel01 * (32 * 8 * 512) + (size_t)jh * (4 * 512);
        const size_t xb = (size_t)mt16 * 32;

        bfx8 xA = *(const bfx8*)&xF[(xb + 0) * 512 + ln * 8];
        bfx8 xB = *(const bfx8*)&xF[(xb + 1) * 512 + ln * 8];
        bfx8 wA[4], wB[4];
        #pragma unroll
        for (int jl = 0; jl < 4; ++jl) {
            wA[jl] = *(const bfx8*)&WFp[(size_t)jl * 512 + ln * 8];
            wB[jl] = *(const bfx8*)&WFp[(size_t)(8 + jl) * 512 + ln * 8];
        }

        f32x4 acc[4];
        #pragma unroll
        for (int jl = 0; jl < 4; ++jl) acc[jl] = (f32x4)(0.f);

        for (int kc = 0; kc < 32; kc += 2) {
            const int kpA = (kc + 2 < 32) ? kc + 2 : kc;
            #pragma unroll
            for (int jl = 0; jl < 4; ++jl) {
                acc[jl] = __builtin_amdgcn_mfma_f32_16x16x32_bf16(xA, wA[jl], acc[jl], 0, 0, 0);
                wA[jl] = *(const bfx8*)&WFp[((size_t)kpA * 8 + jl) * 512 + ln * 8];
            }
            xA = *(const bfx8*)&xF[(xb + kpA) * 512 + ln * 8];
            const int kpB = (kc + 3 < 32) ? kc + 3 : kc + 1;
            #pragma unroll
            for (int jl = 0; jl < 4; ++jl) {
                acc[jl] = __builtin_amdgcn_mfma_f32_16x16x32_bf16(xB, wB[jl], acc[jl], 0, 0, 0);
                wB[jl] = *(const bfx8*)&WFp[((size_t)kpB * 8 + jl) * 512 + ln * 8];
            }
            xB = *(const bfx8*)&xF[(xb + kpB) * 512 + ln * 8];
        }

        const int b = mt16 >> 7;
        const int t16 = mt16 & 127;
        const int mloc16 = t16 * 16;
        __bf16* dstP = (wsel01 == 0 ? QF : KF) + (size_t)b * FRAG_B;

        #pragma unroll
        for (int jl = 0; jl < 4; ++jl) {
            const int j = jh * 4 + jl;
            const int h = j * 16 + lo;
            const float th = theta[h];
            #pragma unroll
            for (int r = 0; r < 4; ++r) {
                const int pos = mloc16 + quad * 4 + r + 1;
                float v = acc[jl][r];
                float partner = __shfl_xor(v, 1, 64);
                float ang = (float)pos * th;
                float rev = ang * 0.15915494309189535f;
                rev -= floorf(rev);
                float sn = __builtin_amdgcn_sinf(rev);
                float cs = __builtin_amdgcn_cosf(rev);
                float res = (h & 1) ? (v * cs - partner * sn)
                                    : (v * cs + partner * sn);
                U16x8 u; u.bf[0] = (__bf16)res;
                T[(quad * 4 + r) * 136 + h] = u.us[0];
            }
        }
        #pragma unroll
        for (int c4l = 0; c4l < 2; ++c4l) {
            const int c4 = jh * 2 + c4l;
            uint4 d = *(const uint4*)&T[(ln & 15) * 136 + c4 * 32 + (ln >> 4) * 8];
            *(uint4*)&dstP[(size_t)(t16 * 4 + c4) * 512 + ln * 8] = d;
        }
    } else {
        const int r2 = bx - 2048;
        const int jh = r2 >> 8;
        const int mt = r2 & 255;
        const int mt16 = mt * 2;

        const __bf16* WFp = WF + (size_t)2 * (32 * 8 * 512) + (size_t)jh * (4 * 512);
        const size_t xb0 = (size_t)mt16 * 32, xb1 = xb0 + 32;

        bfx8 xA[2], xB[2], wA[4], wB[4];
        xA[0] = *(const bfx8*)&xF[(xb0 + 0) * 512 + ln * 8];
        xA[1] = *(const bfx8*)&xF[(xb1 + 0) * 512 + ln * 8];
        xB[0] = *(const bfx8*)&xF[(xb0 + 1) * 512 + ln * 8];
        xB[1] = *(const bfx8*)&xF[(xb1 + 1) * 512 + ln * 8];
        #pragma unroll
        for (int jl = 0; jl < 4; ++jl) {
            wA[jl] = *(const bfx8*)&WFp[(size_t)jl * 512 + ln * 8];
            wB[jl] = *(const bfx8*)&WFp[(size_t)(8 + jl) * 512 + ln * 8];
        }

        f32x4 acc[2][4];
        #pragma unroll
        for (int iq = 0; iq < 2; ++iq)
            #pragma unroll
            for (int jl = 0; jl < 4; ++jl) acc[iq][jl] = (f32x4)(0.f);

        for (int kc = 0; kc < 32; kc += 2) {
            const int kpA = (kc + 2 < 32) ? kc + 2 : kc;
            #pragma unroll
            for (int jl = 0; jl < 4; ++jl) {
                acc[0][jl] = __builtin_amdgcn_mfma_f32_16x16x32_bf16(xA[0], wA[jl], acc[0][jl], 0, 0, 0);
                acc[1][jl] = __builtin_amdgcn_mfma_f32_16x16x32_bf16(xA[1], wA[jl], acc[1][jl], 0, 0, 0);
                wA[jl] = *(const bfx8*)&WFp[((size_t)kpA * 8 + jl) * 512 + ln * 8];
            }
            xA[0] = *(const bfx8*)&xF[(xb0 + kpA) * 512 + ln * 8];
            xA[1] = *(const bfx8*)&xF[(xb1 + kpA) * 512 + ln * 8];
            const int kpB = (kc + 3 < 32) ? kc + 3 : kc + 1;
            #pragma unroll
            for (int jl = 0; jl < 4; ++jl) {
                acc[0][jl] = __builtin_amdgcn_mfma_f32_16x16x32_bf16(xB[0], wB[jl], acc[0][jl], 0, 0, 0);
                acc[1][jl] = __builtin_amdgcn_mfma_f32_16x16x32_bf16(xB[1], wB[jl], acc[1][jl], 0, 0, 0);
                wB[jl] = *(const bfx8*)&WFp[((size_t)kpB * 8 + jl) * 512 + ln * 8];
            }
            xB[0] = *(const bfx8*)&xF[(xb0 + kpB) * 512 + ln * 8];
            xB[1] = *(const bfx8*)&xF[(xb1 + kpB) * 512 + ln * 8];
        }

        const int b = mt >> 6;
        const int kt32 = mt & 63;
        #pragma unroll
        for (int iq = 0; iq < 2; ++iq)
            #pragma unroll
            for (int jl = 0; jl < 4; ++jl) {
                const int j = jh * 4 + jl;
                #pragma unroll
                for (int r = 0; r < 4; ++r) {
                    U16x8 u; u.bf[0] = (__bf16)acc[iq][jl][r];
                    T[(iq * 16 + quad * 4 + r) * 136 + j * 16 + lo] = u.us[0];
                }
            }
        __bf16* dstP = VF + (size_t)b * FRAG_B;
        #pragma unroll
        for (int jl = 0; jl < 4; ++jl) {
            const int j = jh * 4 + jl;
            U16x8 u;
            #pragma unroll
            for (int e = 0; e < 8; ++e)
                u.us[e] = T[((ln >> 4) * 8 + e) * 136 + j * 16 + (ln & 15)];
            *(uint4*)&dstP[(size_t)(kt32 * 8 + j) * 512 + ln * 8] = u.u4;
        }
    }
}

__global__ __launch_bounds__(128) void attn_partial_kernel(
    const __bf16* __restrict__ QF, const __bf16* __restrict__ KF,
    const __bf16* __restrict__ VF,
    __bf16* __restrict__ Opb, float* __restrict__ Ll)
{
    const int bxx = blockIdx.x;            // 2b + (qt&1)
    const int b = bxx >> 1;
    const int qt = (int)blockIdx.y * 2 + (bxx & 1);
    const int c = blockIdx.z;
    const int qbase = qt * 32;
    const int kstart = c << 8;
    if (kstart > qbase) return;
    const int nt = min(8, (qbase + 32 - kstart) >> 5);

    __shared__ __align__(16) unsigned short Pw[2][1280];
    __shared__ float RedO[2 * 8 * 4 * 64];
    __shared__ float RedL[2 * 4 * 64];

    const int tid = threadIdx.x;
    const int w = tid >> 6;
    const int ln = tid & 63;
    const int lo = ln & 15, quad = ln >> 4;
    const int hi8 = quad * 8;

    const __bf16* QFb = QF + (size_t)b * FRAG_B;
    const __bf16* KFb = KF + (size_t)b * FRAG_B;
    const __bf16* VFb = VF + (size_t)b * FRAG_B;

    bfx8 qf[2][4];
    #pragma unroll
    for (int iq = 0; iq < 2; ++iq)
        #pragma unroll
        for (int c4 = 0; c4 < 4; ++c4)
            qf[iq][c4] = *(const bfx8*)&QFb[(size_t)((qt * 2 + iq) * 4 + c4) * 512 + ln * 8];

    f32x4 O[2][8];
    #pragma unroll
    for (int iq = 0; iq < 2; ++iq)
        #pragma unroll
        for (int j = 0; j < 8; ++j) O[iq][j] = (f32x4)(0.f);
    float lsum[2][4];
    #pragma unroll
    for (int iq = 0; iq < 2; ++iq)
        #pragma unroll
        for (int r = 0; r < 4; ++r) lsum[iq][r] = 0.f;

    bfx8 kcur[2][4], knxt[2][4];
    {
        const int kf0 = (kstart + w * 32) >> 4;
        #pragma unroll
        for (int jj = 0; jj < 2; ++jj)
            #pragma unroll
            for (int c4 = 0; c4 < 4; ++c4)
                kcur[jj][c4] = *(const bfx8*)&KFb[(size_t)((kf0 + jj) * 4 + c4) * 512 + ln * 8];
    }

    for (int kt = w; kt < nt; kt += 2) {
        const int k0 = kstart + kt * 32;
        bfx8 vf[8];
        #pragma unroll
        for (int j = 0; j < 8; ++j)
            vf[j] = *(const bfx8*)&VFb[(size_t)((k0 >> 5) * 8 + j) * 512 + ln * 8];
        if (kt + 2 < nt) {
            const int kn16 = (k0 + 64) >> 4;
            #pragma unroll
            for (int jj = 0; jj < 2; ++jj)
                #pragma unroll
                for (int c4 = 0; c4 < 4; ++c4)
                    knxt[jj][c4] = *(const bfx8*)&KFb[(size_t)((kn16 + jj) * 4 + c4) * 512 + ln * 8];
        }

        f32x4 s4[2][2];
        #pragma unroll
        for (int iq = 0; iq < 2; ++iq)
            #pragma unroll
            for (int jj = 0; jj < 2; ++jj) s4[iq][jj] = (f32x4)(0.f);
        #pragma unroll
        for (int c4 = 0; c4 < 4; ++c4)
            #pragma unroll
            for (int iq = 0; iq < 2; ++iq)
                #pragma unroll
                for (int jj = 0; jj < 2; ++jj)
                    s4[iq][jj] = __builtin_amdgcn_mfma_f32_16x16x32_bf16(qf[iq][c4], kcur[jj][c4], s4[iq][jj], 0, 0, 0);

        const bool needMask = (k0 + 31 > qbase);
        #pragma unroll
        for (int iq = 0; iq < 2; ++iq)
            #pragma unroll
            for (int jj = 0; jj < 2; ++jj)
                #pragma unroll
                for (int r = 0; r < 4; ++r) {
                    const int col = k0 + jj * 16 + lo;
                    const int row = qbase + iq * 16 + quad * 4 + r;
                    float p = __expf(s4[iq][jj][r] * 0.03125f);
                    if (needMask && col > row) p = 0.f;
                    lsum[iq][r] += p;
                    U16x8 u; u.bf[0] = (__bf16)p;
                    Pw[w][iq * 640 + (quad * 4 + r) * 40 + jj * 16 + lo] = u.us[0];
                }

        bfx8 pf0 = *(const bfx8*)&Pw[w][lo * 40 + hi8];
        bfx8 pf1 = *(const bfx8*)&Pw[w][640 + lo * 40 + hi8];
        #pragma unroll
        for (int j = 0; j < 8; ++j) {
            O[0][j] = __builtin_amdgcn_mfma_f32_16x16x32_bf16(pf0, vf[j], O[0][j], 0, 0, 0);
            O[1][j] = __builtin_amdgcn_mfma_f32_16x16x32_bf16(pf1, vf[j], O[1][j], 0, 0, 0);
        }

        #pragma unroll
        for (int jj = 0; jj < 2; ++jj)
            #pragma unroll
            for (int c4 = 0; c4 < 4; ++c4) kcur[jj][c4] = knxt[jj][c4];
    }

    #pragma unroll
    for (int off = 1; off < 16; off <<= 1)
        #pragma unroll
        for (int iq = 0; iq < 2; ++iq)
            #pragma unroll
            for (int r = 0; r < 4; ++r) lsum[iq][r] += __shfl_xor(lsum[iq][r], off, 64);

    if (w == 1) {
        #pragma unroll
        for (int iq = 0; iq < 2; ++iq)
            #pragma unroll
            for (int j = 0; j < 8; ++j)
                #pragma unroll
                for (int r = 0; r < 4; ++r)
                    RedO[((iq * 8 + j) * 4 + r) * 64 + ln] = O[iq][j][r];
        #pragma unroll
        for (int iq = 0; iq < 2; ++iq)
            #pragma unroll
            for (int r = 0; r < 4; ++r)
                RedL[(iq * 4 + r) * 64 + ln] = lsum[iq][r];
    }
    __syncthreads();
    if (w == 0) {
        #pragma unroll
        for (int iq = 0; iq < 2; ++iq)
            #pragma unroll
            for (int j = 0; j < 8; ++j)
                #pragma unroll
                for (int r = 0; r < 4; ++r)
                    O[iq][j][r] += RedO[((iq * 8 + j) * 4 + r) * 64 + ln];
        #pragma unroll
        for (int iq = 0; iq < 2; ++iq)
            #pragma unroll
            for (int r = 0; r < 4; ++r)
                lsum[iq][r] += RedL[(iq * 4 + r) * 64 + ln];

        const size_t sb = (size_t)b * SLOTS + slot_base32(qt) + c;
        #pragma unroll
        for (int iq = 0; iq < 2; ++iq)
            #pragma unroll
            for (int j = 0; j < 8; ++j) {
                U16x8 u;
                u.bf[0] = (__bf16)O[iq][j][0]; u.bf[1] = (__bf16)O[iq][j][1];
                u.bf[2] = (__bf16)O[iq][j][2]; u.bf[3] = (__bf16)O[iq][j][3];
                *(uint2*)&Opb[((sb * 2 + iq) * 8 + j) * 256 + ln * 4] = make_uint2(u.ui[0], u.ui[1]);
            }
        if (lo == 0) {
            #pragma unroll
            for (int iq = 0; iq < 2; ++iq)
                #pragma unroll
                for (int r = 0; r < 4; ++r)
                    Ll[sb * 32 + iq * 16 + quad * 4 + r] = lsum[iq][r];
        }
    }
}

__global__ __launch_bounds__(128) void attn_merge_kernel(
    const __bf16* __restrict__ Opb, const float* __restrict__ Ll,
    float* __restrict__ out)
{
    const int qt = blockIdx.x, b = blockIdx.y, jh2 = blockIdx.z;
    const int g = qt >> 3, nc = g + 1;
    const size_t base = (size_t)b * SLOTS + slot_base32(qt);

    __shared__ float Lsh[8][32];
    const int tid = threadIdx.x;
    const int iq = tid >> 6, ln = tid & 63;
    const int lo = ln & 15, quad = ln >> 4;

    for (int idx = tid; idx < nc * 32; idx += 128)
        Lsh[idx >> 5][idx & 31] = Ll[(base + (idx >> 5)) * 32 + (idx & 31)];
    __syncthreads();

    float acc[4][4];
    #pragma unroll
    for (int jl = 0; jl < 4; ++jl)
        #pragma unroll
        for (int r = 0; r < 4; ++r) acc[jl][r] = 0.f;

    for (int cc = 0; cc < nc; ++cc) {
        #pragma unroll
        for (int jl = 0; jl < 4; ++jl) {
            const int j = jh2 * 4 + jl;
            uint2 d = *(const uint2*)&Opb[(((base + cc) * 2 + iq) * 8 + j) * 256 + ln * 4];
            U16x8 u; u.ui[0] = d.x; u.ui[1] = d.y;
            #pragma unroll
            for (int r = 0; r < 4; ++r) acc[jl][r] += (float)u.bf[r];
        }
    }

    #pragma unroll
    for (int r = 0; r < 4; ++r) {
        const int row = iq * 16 + quad * 4 + r;
        float l = 0.f;
        for (int cc = 0; cc < nc; ++cc) l += Lsh[cc][row];
        const float rl = 1.0f / l;
        #pragma unroll
        for (int jl = 0; jl < 4; ++jl) {
            const int j = jh2 * 4 + jl;
            out[((size_t)b * T_SEQ + qt * 32 + row) * DH + j * 16 + lo] = acc[jl][r] * rl;
        }
    }
}

// ============================================================================
// FUSED COOPERATIVE PATH — grid-size-agnostic phases, fenced grid syncs.
// ============================================================================

__device__ __forceinline__ void qkv_task(
    int t, unsigned short* T,
    const __bf16* __restrict__ xF, const __bf16* __restrict__ WF,
    const float* __restrict__ theta,
    __bf16* __restrict__ QF, __bf16* __restrict__ KF, __bf16* __restrict__ VF,
    int ln, int lo, int quad)
{
    if (t < 2048) {
        const int wsel01 = t >> 10;
        const int sub = (t >> 8) & 3;
        const int iq = sub >> 1, jh = sub & 1;
        const int mt = t & 255;
        const int mt16 = mt * 2 + iq;

        const __bf16* WFp = WF + (size_t)wsel01 * (32 * 8 * 512) + (size_t)jh * (4 * 512);
        const size_t xb = (size_t)mt16 * 32;

        bfx8 xA = *(const bfx8*)&xF[(xb + 0) * 512 + ln * 8];
        bfx8 xB = *(const bfx8*)&xF[(xb + 1) * 512 + ln * 8];
        bfx8 wA[4], wB[4];
        #pragma unroll
        for (int jl = 0; jl < 4; ++jl) {
            wA[jl] = *(const bfx8*)&WFp[(size_t)jl * 512 + ln * 8];
            wB[jl] = *(const bfx8*)&WFp[(size_t)(8 + jl) * 512 + ln * 8];
        }

        f32x4 acc[4];
        #pragma unroll
        for (int jl = 0; jl < 4; ++jl) acc[jl] = (f32x4)(0.f);

        for (int kc = 0; kc < 32; kc += 2) {
            const int kpA = (kc + 2 < 32) ? kc + 2 : kc;
            #pragma unroll
            for (int jl = 0; jl < 4; ++jl) {
                acc[jl] = __builtin_amdgcn_mfma_f32_16x16x32_bf16(xA, wA[jl], acc[jl], 0, 0, 0);
                wA[jl] = *(const bfx8*)&WFp[((size_t)kpA * 8 + jl) * 512 + ln * 8];
            }
            xA = *(const bfx8*)&xF[(xb + kpA) * 512 + ln * 8];
            const int kpB = (kc + 3 < 32) ? kc + 3 : kc + 1;
            #pragma unroll
            for (int jl = 0; jl < 4; ++jl) {
                acc[jl] = __builtin_amdgcn_mfma_f32_16x16x32_bf16(xB, wB[jl], acc[jl], 0, 0, 0);
                wB[jl] = *(const bfx8*)&WFp[((size_t)kpB * 8 + jl) * 512 + ln * 8];
            }
            xB = *(const bfx8*)&xF[(xb + kpB) * 512 + ln * 8];
        }

        const int b = mt16 >> 7;
        const int t16 = mt16 & 127;
        const int mloc16 = t16 * 16;
        __bf16* dstP = (wsel01 == 0 ? QF : KF) + (size_t)b * FRAG_B;

        #pragma unroll
        for (int jl = 0; jl < 4; ++jl) {
            const int j = jh * 4 + jl;
            const int h = j * 16 + lo;
            const float th = theta[h];
            #pragma unroll
            for (int r = 0; r < 4; ++r) {
                const int pos = mloc16 + quad * 4 + r + 1;
                float v = acc[jl][r];
                float partner = __shfl_xor(v, 1, 64);
                float ang = (float)pos * th;
                float rev = ang * 0.15915494309189535f;
                rev -= floorf(rev);
                float sn = __builtin_amdgcn_sinf(rev);
                float cs = __builtin_amdgcn_cosf(rev);
                float res = (h & 1) ? (v * cs - partner * sn)
                                    : (v * cs + partner * sn);
                U16x8 u; u.bf[0] = (__bf16)res;
                T[(quad * 4 + r) * 136 + h] = u.us[0];
            }
        }
        #pragma unroll
        for (int c4l = 0; c4l < 2; ++c4l) {
            const int c4 = jh * 2 + c4l;
            uint4 d = *(const uint4*)&T[(ln & 15) * 136 + c4 * 32 + (ln >> 4) * 8];
            *(uint4*)&dstP[(size_t)(t16 * 4 + c4) * 512 + ln * 8] = d;
        }
    } else {
        const int r2 = t - 2048;
        const int jh = r2 >> 8;
        const int mt = r2 & 255;
        const int mt16 = mt * 2;

        const __bf16* WFp = WF + (size_t)2 * (32 * 8 * 512) + (size_t)jh * (4 * 512);
        const size_t xb0 = (size_t)mt16 * 32, xb1 = xb0 + 32;

        bfx8 xA[2], xB[2], wA[4], wB[4];
        xA[0] = *(const bfx8*)&xF[(xb0 + 0) * 512 + ln * 8];
        xA[1] = *(const bfx8*)&xF[(xb1 + 0) * 512 + ln * 8];
        xB[0] = *(const bfx8*)&xF[(xb0 + 1) * 512 + ln * 8];
        xB[1] = *(const bfx8*)&xF[(xb1 + 1) * 512 + ln * 8];
        #pragma unroll
        for (int jl = 0; jl < 4; ++jl) {
            wA[jl] = *(const bfx8*)&WFp[(size_t)jl * 512 + ln * 8];
            wB[jl] = *(const bfx8*)&WFp[(size_t)(8 + jl) * 512 + ln * 8];
        }

        f32x4 acc[2][4];
        #pragma unroll
        for (int iq = 0; iq < 2; ++iq)
            #pragma unroll
            for (int jl = 0; jl < 4; ++jl) acc[iq][jl] = (f32x4)(0.f);

        for (int kc = 0; kc < 32; kc += 2) {
            const int kpA = (kc + 2 < 32) ? kc + 2 : kc;
            #pragma unroll
            for (int jl = 0; jl < 4; ++jl) {
                acc[0][jl] = __builtin_amdgcn_mfma_f32_16x16x32_bf16(xA[0], wA[jl], acc[0][jl], 0, 0, 0);
                acc[1][jl] = __builtin_amdgcn_mfma_f32_16x16x32_bf16(xA[1], wA[jl], acc[1][jl], 0, 0, 0);
                wA[jl] = *(const bfx8*)&WFp[((size_t)kpA * 8 + jl) * 512 + ln * 8];
            }
            xA[0] = *(const bfx8*)&xF[(xb0 + kpA) * 512 + ln * 8];
            xA[1] = *(const bfx8*)&xF[(xb1 + kpA) * 512 + ln * 8];
            const int kpB = (kc + 3 < 32) ? kc + 3 : kc + 1;
            #pragma unroll
            for (int jl = 0; jl < 4; ++jl) {
                acc[0][jl] = __builtin_amdgcn_mfma_f32_16x16x32_bf16(xB[0], wB[jl], acc[0][jl], 0, 0, 0);
                acc[1][jl] = __builtin_amdgcn_mfma_f32_16x16x32_bf16(xB[1], wB[jl], acc[1][jl], 0, 0, 0);
                wB[jl] = *(const bfx8*)&WFp[((size_t)kpB * 8 + jl) * 512 + ln * 8];
            }
            xB[0] = *(const bfx8*)&xF[(xb0 + kpB) * 512 + ln * 8];
            xB[1] = *(const bfx8*)&xF[(xb1 + kpB) * 512 + ln * 8];
        }

        const int b = mt >> 6;
        const int kt32 = mt & 63;
        #pragma unroll
        for (int iq = 0; iq < 2; ++iq)
            #pragma unroll
            for (int jl = 0; jl < 4; ++jl) {
                const int j = jh * 4 + jl;
                #pragma unroll
                for (int r = 0; r < 4; ++r) {
                    U16x8 u; u.bf[0] = (__bf16)acc[iq][jl][r];
                    T[(iq * 16 + quad * 4 + r) * 136 + j * 16 + lo] = u.us[0];
                }
            }
        __bf16* dstP = VF + (size_t)b * FRAG_B;
        #pragma unroll
        for (int jl = 0; jl < 4; ++jl) {
            const int j = jh * 4 + jl;
            U16x8 u;
            #pragma unroll
            for (int e = 0; e < 8; ++e)
                u.us[e] = T[((ln >> 4) * 8 + e) * 136 + j * 16 + (ln & 15)];
            *(uint4*)&dstP[(size_t)(kt32 * 8 + j) * 512 + ln * 8] = u.u4;
        }
    }
}

__global__ __launch_bounds__(256, 2) void fused_kernel(
    const float* __restrict__ x,
    const float* __restrict__ Wq, const float* __restrict__ Wk,
    const float* __restrict__ Wv, const float* __restrict__ theta,
    __bf16* __restrict__ xF, __bf16* __restrict__ WF,
    __bf16* __restrict__ QF, __bf16* __restrict__ KF, __bf16* __restrict__ VF,
    __bf16* __restrict__ Opb, float* __restrict__ Ll,
    float* __restrict__ out)
{
    __shared__ __align__(16) unsigned char SMEM[34816];   // max phase need (qkv 4xT)
    cg::grid_group grid = cg::this_grid();

    const int nblk = gridDim.x;        // 256 or 512 (multiple of 8)
    const int bid = blockIdx.x;
    const int tid = threadIdx.x;
    const int w = tid >> 6;            // wave 0..3
    const int ln = tid & 63;
    const int lo = ln & 15, quad = ln >> 4;
    const int wid = bid * 4 + w;

    // ---------------- Phase P: prep ------------------------------------------------
    {
        unsigned short* Xs = (unsigned short*)SMEM;       // 9 KB
        for (int task = bid; task < 2048 + 192; task += nblk) {
            if (task < 2048) {
                const int m0 = (task >> 4) * 64;
                const int k0 = (task & 15) * 64;
                const int row = tid >> 2, cs = (tid & 3) * 16;
                const float* xp = x + (size_t)(m0 + row) * D_MODEL + k0 + cs;
                float4 a0 = *(const float4*)xp;
                float4 a1 = *(const float4*)(xp + 4);
                float4 a2 = *(const float4*)(xp + 8);
                float4 a3 = *(const float4*)(xp + 12);
                *(uint4*)&Xs[row * 72 + cs]     = cvt8u(a0, a1);
                *(uint4*)&Xs[row * 72 + cs + 8] = cvt8u(a2, a3);
                __syncthreads();
                const int L = tid & 63;
                #pragma unroll
                for (int rr = 0; rr < 2; ++rr) {
                    const int fid = rr * 4 + (tid >> 6);
                    const int mtl = fid >> 1, kcl = fid & 1;
                    uint4 d = *(const uint4*)&Xs[(mtl * 16 + (L & 15)) * 72 + kcl * 32 + (L >> 4) * 8];
                    const size_t frag = (size_t)((m0 >> 4) + mtl) * 32 + (k0 >> 5) + kcl;
                    *(uint4*)&xF[frag * 512 + L * 8] = d;
                }
                __syncthreads();
            } else {
                const int i = (task - 2048) * 256 + tid;
                const int wsel = i >> 14;
                const int i2 = i & 16383;
                const int kc = i2 >> 9, j = (i2 >> 6) & 7, l2 = i2 & 63;
                const int lo2 = l2 & 15, q2 = l2 >> 4;
                const float* src = (wsel == 0) ? Wq : (wsel == 1) ? Wk : Wv;
                const float* p = src + (size_t)(j * 16 + lo2) * D_MODEL + kc * 32 + q2 * 8;
                float4 a = *(const float4*)p;
                float4 b = *(const float4*)(p + 4);
                *(uint4*)&WF[(size_t)((wsel * 32 + kc) * 8 + j) * 512 + l2 * 8] = cvt8u(a, b);
            }
        }
    }
    __threadfence();
    grid.sync();
    __threadfence();

    // ---------------- Phase A: QKV -------------------------------------------------
    {
        unsigned short* T = (unsigned short*)SMEM + (size_t)w * (32 * 136);
        const int nw = nblk * 4;
        for (int t = wid; t < 2560; t += nw)
            qkv_task(t, T, xF, WF, theta, QF, KF, VF, ln, lo, quad);
    }
    __threadfence();
    grid.sync();
    __threadfence();

    // ---------------- Phase B: attention partials (1-wave chunks) ------------------
    {
        const int cls = bid & 7;                  // = XCD -> pinned (b, qt-parity)
        const int b = cls >> 1, parity = cls & 1;
        const int strideR = (nblk >> 3) * 4;
        unsigned short* Pw = (unsigned short*)SMEM + (size_t)w * 1280;
        const int hi8 = quad * 8;

        const __bf16* QFb = QF + (size_t)b * FRAG_B;
        const __bf16* KFb = KF + (size_t)b * FRAG_B;
        const __bf16* VFb = VF + (size_t)b * FRAG_B;

        for (int rk = (bid >> 3) * 4 + w; rk < 144; rk += strideR) {
            int qt2 = 0, accb = 0;
            while (true) { int ncg = (qt2 >> 2) + 1; if (rk < accb + ncg) break; accb += ncg; ++qt2; }
            const int c = rk - accb;
            const int qt = qt2 * 2 + parity;
            const int qbase = qt * 32;
            const int kstart = c << 8;
            const int nt = min(8, (qbase + 32 - kstart) >> 5);

            bfx8 qf[2][4];
            #pragma unroll
            for (int iq = 0; iq < 2; ++iq)
                #pragma unroll
                for (int c4 = 0; c4 < 4; ++c4)
                    qf[iq][c4] = *(const bfx8*)&QFb[(size_t)((qt * 2 + iq) * 4 + c4) * 512 + ln * 8];

            f32x4 O[2][8];
            #pragma unroll
            for (int iq = 0; iq < 2; ++iq)
                #pragma unroll
                for (int j = 0; j < 8; ++j) O[iq][j] = (f32x4)(0.f);
            float lsum[2][4];
            #pragma unroll
            for (int iq = 0; iq < 2; ++iq)
                #pragma unroll
                for (int r = 0; r < 4; ++r) lsum[iq][r] = 0.f;

            bfx8 kcur[2][4], knxt[2][4];
            #pragma unroll
            for (int jj = 0; jj < 2; ++jj)
                #pragma unroll
                for (int c4 = 0; c4 < 4; ++c4)
                    kcur[jj][c4] = *(const bfx8*)&KFb[(size_t)(((kstart >> 4) + jj) * 4 + c4) * 512 + ln * 8];

            for (int kt = 0; kt < nt; ++kt) {
                const int k0 = kstart + kt * 32;
                bfx8 vf[8];
                #pragma unroll
                for (int j = 0; j < 8; ++j)
                    vf[j] = *(const bfx8*)&VFb[(size_t)((k0 >> 5) * 8 + j) * 512 + ln * 8];
                if (kt + 1 < nt) {
                    const int kn16 = (k0 + 32) >> 4;
                    #pragma unroll
                    for (int jj = 0; jj < 2; ++jj)
                        #pragma unroll
                        for (int c4 = 0; c4 < 4; ++c4)
                            knxt[jj][c4] = *(const bfx8*)&KFb[(size_t)((kn16 + jj) * 4 + c4) * 512 + ln * 8];
                }

                f32x4 s4[2][2];
                #pragma unroll
                for (int iq = 0; iq < 2; ++iq)
                    #pragma unroll
                    for (int jj = 0; jj < 2; ++jj) s4[iq][jj] = (f32x4)(0.f);
                #pragma unroll
                for (int c4 = 0; c4 < 4; ++c4)
                    #pragma unroll
                    for (int iq = 0; iq < 2; ++iq)
                        #pragma unroll
                        for (int jj = 0; jj < 2; ++jj)
                            s4[iq][jj] = __builtin_amdgcn_mfma_f32_16x16x32_bf16(qf[iq][c4], kcur[jj][c4], s4[iq][jj], 0, 0, 0);

                const bool needMask = (k0 + 31 > qbase);
                #pragma unroll
                for (int iq = 0; iq < 2; ++iq)
                    #pragma unroll
                    for (int jj = 0; jj < 2; ++jj)
                        #pragma unroll
                        for (int r = 0; r < 4; ++r) {
                            const int col = k0 + jj * 16 + lo;
                            const int row = qbase + iq * 16 + quad * 4 + r;
                            float p = __expf(s4[iq][jj][r] * 0.03125f);
                            if (needMask && col > row) p = 0.f;
                            lsum[iq][r] += p;
                            U16x8 u; u.bf[0] = (__bf16)p;
                            Pw[iq * 640 + (quad * 4 + r) * 40 + jj * 16 + lo] = u.us[0];
                        }

                bfx8 pf0 = *(const bfx8*)&Pw[lo * 40 + hi8];
                bfx8 pf1 = *(const bfx8*)&Pw[640 + lo * 40 + hi8];
                #pragma unroll
                for (int j = 0; j < 8; ++j) {
                    O[0][j] = __builtin_amdgcn_mfma_f32_16x16x32_bf16(pf0, vf[j], O[0][j], 0, 0, 0);
                    O[1][j] = __builtin_amdgcn_mfma_f32_16x16x32_bf16(pf1, vf[j], O[1][j], 0, 0, 0);
                }

                #pragma unroll
                for (int jj = 0; jj < 2; ++jj)
                    #pragma unroll
                    for (int c4 = 0; c4 < 4; ++c4) kcur[jj][c4] = knxt[jj][c4];
            }

            #pragma unroll
            for (int off = 1; off < 16; off <<= 1)
                #pragma unroll
                for (int iq = 0; iq < 2; ++iq)
                    #pragma unroll
                    for (int r = 0; r < 4; ++r) lsum[iq][r] += __shfl_xor(lsum[iq][r], off, 64);

            const size_t sb = (size_t)b * SLOTS + slot_base32(qt) + c;
            #pragma unroll
            for (int iq = 0; iq < 2; ++iq)
                #pragma unroll
                for (int j = 0; j < 8; ++j) {
                    U16x8 u;
                    u.bf[0] = (__bf16)O[iq][j][0]; u.bf[1] = (__bf16)O[iq][j][1];
                    u.bf[2] = (__bf16)O[iq][j][2]; u.bf[3] = (__bf16)O[iq][j][3];
                    *(uint2*)&Opb[((sb * 2 + iq) * 8 + j) * 256 + ln * 4] = make_uint2(u.ui[0], u.ui[1]);
                }
            if (lo == 0) {
                #pragma unroll
                for (int iq = 0; iq < 2; ++iq)
                    #pragma unroll
                    for (int r = 0; r < 4; ++r)
                        Ll[sb * 32 + iq * 16 + quad * 4 + r] = lsum[iq][r];
            }
        }
    }
    __threadfence();
    grid.sync();
    __threadfence();

    // ---------------- Phase C: merge ------------------------------------------------
    for (int mb = bid; mb < 256; mb += nblk) {
        const int qt = mb >> 2, b = mb & 3;
        const int nc = (qt >> 3) + 1;
        const size_t base = (size_t)b * SLOTS + slot_base32(qt);

        float* Lsh = (float*)SMEM;    // [8][32] flat
        for (int idx = tid; idx < nc * 32; idx += 256)
            Lsh[idx] = Ll[(base + (idx >> 5)) * 32 + (idx & 31)];
        __syncthreads();

        const int jh2 = tid >> 7;
        const int iq = (tid >> 6) & 1;
        const int l2 = tid & 63;
        const int lo2 = l2 & 15, q2 = l2 >> 4;

        float acc[4][4];
        #pragma unroll
        for (int jl = 0; jl < 4; ++jl)
            #pragma unroll
            for (int r = 0; r < 4; ++r) acc[jl][r] = 0.f;

        for (int cc = 0; cc < nc; ++cc) {
            #pragma unroll
            for (int jl = 0; jl < 4; ++jl) {
                const int j = jh2 * 4 + jl;
                uint2 d = *(const uint2*)&Opb[(((base + cc) * 2 + iq) * 8 + j) * 256 + l2 * 4];
                U16x8 u; u.ui[0] = d.x; u.ui[1] = d.y;
                #pragma unroll
                for (int r = 0; r < 4; ++r) acc[jl][r] += (float)u.bf[r];
            }
        }

        #pragma unroll
        for (int r = 0; r < 4; ++r) {
            const int row = iq * 16 + q2 * 4 + r;
            float l = 0.f;
            for (int cc = 0; cc < nc; ++cc) l += Lsh[cc * 32 + row];
            const float rl = 1.0f / l;
            #pragma unroll
            for (int jl = 0; jl < 4; ++jl) {
                const int j = jh2 * 4 + jl;
                out[((size_t)b * T_SEQ + qt * 32 + row) * DH + j * 16 + lo2] = acc[jl][r] * rl;
            }
        }
        __syncthreads();   // protect Lsh if looping
    }
}

extern "C" void kernel_launch(void* const* d_in, const int* in_sizes, int n_in,
                              void* d_out, int out_size, void* d_ws, size_t ws_size,
                              hipStream_t stream) {
    const float* x     = (const float*)d_in[0];
    const float* Wq    = (const float*)d_in[1];
    const float* Wk    = (const float*)d_in[2];
    const float* Wv    = (const float*)d_in[3];
    const float* theta = (const float*)d_in[4];
    float* out = (float*)d_out;

    const int M = in_sizes[0] / D_MODEL;   // B*T = 8192
    const int B = M / T_SEQ;               // 4

    __bf16* xF  = (__bf16*)d_ws;                     // M*1024 bf16
    __bf16* WF  = xF + (size_t)M * D_MODEL;          // 3*32*8*512
    __bf16* QF  = WF + (size_t)3 * 32 * 8 * 512;
    __bf16* KF  = QF + (size_t)B * FRAG_B;
    __bf16* VF  = KF + (size_t)B * FRAG_B;
    __bf16* Opb = VF + (size_t)B * FRAG_B;
    float*  Ll  = (float*)(Opb + (size_t)B * SLOTS * 2 * 8 * 256);

    // One-time capability probe (host-side queries only; graph-capture safe).
    static int coopGrid = -1;
    if (coopGrid < 0) {
        int attr = 0, mb = 0;
        hipError_t e1 = hipDeviceGetAttribute(&attr, hipDeviceAttributeCooperativeLaunch, 0);
        hipError_t e2 = hipOccupancyMaxActiveBlocksPerMultiprocessor(&mb, fused_kernel, 256, 0);
        coopGrid = (e1 == hipSuccess && attr != 0 && e2 == hipSuccess && mb >= 1)
                   ? ((mb >= 2) ? 512 : 256) : 0;
    }

    bool launched = false;
    if (coopGrid > 0) {
        void* args[] = { (void*)&x, (void*)&Wq, (void*)&Wk, (void*)&Wv, (void*)&theta,
                         (void*)&xF, (void*)&WF, (void*)&QF, (void*)&KF, (void*)&VF,
                         (void*)&Opb, (void*)&Ll, (void*)&out };
        hipError_t err = hipLaunchCooperativeKernel((void*)fused_kernel, dim3(coopGrid),
                                                    dim3(256), args, 0, stream);
        launched = (err == hipSuccess);
        if (!launched) coopGrid = 0;   // don't retry on later calls
    }

    if (!launched) {
        // Proven round-6 path (122.4 us).
        const int nxb = (M / 64) * 16;               // 2048 xcvt blocks
        prep_kernel<<<dim3(nxb + 192), 256, 0, stream>>>(x, Wq, Wk, Wv, xF, WF, nxb);
        qkv_kernel<<<dim3(2048 + 512), 64, 0, stream>>>(xF, WF, theta, QF, KF, VF);
        attn_partial_kernel<<<dim3(2 * B, T_SEQ / 64, 8), 128, 0, stream>>>(QF, KF, VF, Opb, Ll);
        attn_merge_kernel<<<dim3(T_SEQ / 32, B, 2), 128, 0, stream>>>(Opb, Ll, out);
    }
}

// Round 10
// 170.916 us; speedup vs baseline: 2.1322x; 2.1322x over previous
//
#include <hip/hip_runtime.h>
#include <math.h>

#define T_SEQ 2048
#define D_MODEL 1024
#define DH 128
#define SLOTS 288          // per batch: sum_{qt=0..63} ((qt>>3)+1)
#define FRAG_B 262144      // frag-plane elems per batch: 128*4*512 (= 64*8*512)

typedef __bf16 bfx8 __attribute__((ext_vector_type(8)));
typedef float f32x4 __attribute__((ext_vector_type(4)));

union U16x8 { uint4 u4; unsigned int ui[4]; unsigned short us[8]; __bf16 bf[8]; bfx8 v; };

__device__ inline uint4 cvt8u(float4 a, float4 b) {
    U16x8 u;
    u.bf[0] = (__bf16)a.x; u.bf[1] = (__bf16)a.y; u.bf[2] = (__bf16)a.z; u.bf[3] = (__bf16)a.w;
    u.bf[4] = (__bf16)b.x; u.bf[5] = (__bf16)b.y; u.bf[6] = (__bf16)b.z; u.bf[7] = (__bf16)b.w;
    return u.u4;
}

__device__ inline int slot_base32(int qt) {   // sum_{i<qt} ((i>>3)+1)
    int g = qt >> 3, j = qt & 7;
    return 4 * g * (g + 1) + j * (g + 1);
}

// ---------------- Kernel P: prep — x -> xF (A-frag order), W -> WF (B-frag order) ----
// blocks [0, nxb): xcvt. 64m x 64k tile via LDS transpose-to-frag; coalesced in/out.
// blocks [nxb, nxb+192): wcvt. One-pass gather of 1.5 MB W into B-frag order.
// Block nxb additionally zeroes the 256 per-(b,qt) merge counters (stream-ordered
// before attn; safe against workspace poisoning).
__global__ __launch_bounds__(256) void prep_kernel(
    const float* __restrict__ x,
    const float* __restrict__ Wq, const float* __restrict__ Wk,
    const float* __restrict__ Wv,
    __bf16* __restrict__ xF, __bf16* __restrict__ WF,
    unsigned int* __restrict__ Cnt, int nxb)
{
    const int bi = blockIdx.x;
    const int tid = threadIdx.x;

    if (bi < nxb) {
        __shared__ __align__(16) unsigned short Xs[64 * 72];   // 9 KB
        const int m0 = (bi >> 4) * 64;
        const int k0 = (bi & 15) * 64;
        const int row = tid >> 2, cs = (tid & 3) * 16;
        const float* xp = x + (size_t)(m0 + row) * D_MODEL + k0 + cs;
        float4 a0 = *(const float4*)xp;
        float4 a1 = *(const float4*)(xp + 4);
        float4 a2 = *(const float4*)(xp + 8);
        float4 a3 = *(const float4*)(xp + 12);
        *(uint4*)&Xs[row * 72 + cs]     = cvt8u(a0, a1);
        *(uint4*)&Xs[row * 72 + cs + 8] = cvt8u(a2, a3);
        __syncthreads();
        const int L = tid & 63;
        #pragma unroll
        for (int rr = 0; rr < 2; ++rr) {
            const int fid = rr * 4 + (tid >> 6);   // 8 local frags: mtl(4) x kcl(2)
            const int mtl = fid >> 1, kcl = fid & 1;
            uint4 d = *(const uint4*)&Xs[(mtl * 16 + (L & 15)) * 72 + kcl * 32 + (L >> 4) * 8];
            const size_t frag = (size_t)((m0 >> 4) + mtl) * 32 + (k0 >> 5) + kcl;
            *(uint4*)&xF[frag * 512 + L * 8] = d;
        }
    } else {
        if (bi == nxb) Cnt[tid] = 0;               // 256 counters = B*64
        const int i = (bi - nxb) * 256 + tid;      // 49152 threads
        const int wsel = i >> 14;
        const int i2 = i & 16383;
        const int kc = i2 >> 9, j = (i2 >> 6) & 7, ln = i2 & 63;
        const int lo = ln & 15, quad = ln >> 4;
        const float* src = (wsel == 0) ? Wq : (wsel == 1) ? Wk : Wv;
        const float* p = src + (size_t)(j * 16 + lo) * D_MODEL + kc * 32 + quad * 8;
        float4 a = *(const float4*)p;
        float4 b = *(const float4*)(p + 4);
        *(uint4*)&WF[(size_t)((wsel * 32 + kc) * 8 + j) * 512 + ln * 8] = cvt8u(a, b);
    }
}

// ---------------- Kernel A: QKV — fine-split wave GEMM + RoPE (round-4 geometry) ----
// 2560 single-wave blocks (10/CU = 2.5 waves/SIMD) — measured optimum of this family.
__global__ __launch_bounds__(64) void qkv_kernel(
    const __bf16* __restrict__ xF, const __bf16* __restrict__ WF,
    const float* __restrict__ theta,
    __bf16* __restrict__ QF, __bf16* __restrict__ KF, __bf16* __restrict__ VF)
{
    __shared__ __align__(16) unsigned short T[32 * 136];   // 8.7 KB wave-private

    const int bx = blockIdx.x;
    const int ln = threadIdx.x;
    const int lo = ln & 15, quad = ln >> 4;

    if (bx < 2048) {
        const int wsel01 = bx >> 10;           // 0=Q, 1=K
        const int sub = (bx >> 8) & 3;
        const int iq = sub >> 1, jh = sub & 1;
        const int mt = bx & 255;
        const int mt16 = mt * 2 + iq;

        const __bf16* WFp = WF + (size_t)wsel01 * (32 * 8 * 512) + (size_t)jh * (4 * 512);
        const size_t xb = (size_t)mt16 * 32;

        bfx8 xA = *(const bfx8*)&xF[(xb + 0) * 512 + ln * 8];
        bfx8 xB = *(const bfx8*)&xF[(xb + 1) * 512 + ln * 8];
        bfx8 wA[4], wB[4];
        #pragma unroll
        for (int jl = 0; jl < 4; ++jl) {
            wA[jl] = *(const bfx8*)&WFp[(size_t)jl * 512 + ln * 8];
            wB[jl] = *(const bfx8*)&WFp[(size_t)(8 + jl) * 512 + ln * 8];
        }

        f32x4 acc[4];
        #pragma unroll
        for (int jl = 0; jl < 4; ++jl) acc[jl] = (f32x4)(0.f);

        for (int kc = 0; kc < 32; kc += 2) {
            const int kpA = (kc + 2 < 32) ? kc + 2 : kc;   // tail clamp: harmless reload
            #pragma unroll
            for (int jl = 0; jl < 4; ++jl) {
                acc[jl] = __builtin_amdgcn_mfma_f32_16x16x32_bf16(xA, wA[jl], acc[jl], 0, 0, 0);
                wA[jl] = *(const bfx8*)&WFp[((size_t)kpA * 8 + jl) * 512 + ln * 8];
            }
            xA = *(const bfx8*)&xF[(xb + kpA) * 512 + ln * 8];
            const int kpB = (kc + 3 < 32) ? kc + 3 : kc + 1;
            #pragma unroll
            for (int jl = 0; jl < 4; ++jl) {
                acc[jl] = __builtin_amdgcn_mfma_f32_16x16x32_bf16(xB, wB[jl], acc[jl], 0, 0, 0);
                wB[jl] = *(const bfx8*)&WFp[((size_t)kpB * 8 + jl) * 512 + ln * 8];
            }
            xB = *(const bfx8*)&xF[(xb + kpB) * 512 + ln * 8];
        }

        const int b = mt16 >> 7;
        const int t16 = mt16 & 127;
        const int mloc16 = t16 * 16;
        __bf16* dstP = (wsel01 == 0 ? QF : KF) + (size_t)b * FRAG_B;

        #pragma unroll
        for (int jl = 0; jl < 4; ++jl) {
            const int j = jh * 4 + jl;
            const int h = j * 16 + lo;
            const float th = theta[h];
            #pragma unroll
            for (int r = 0; r < 4; ++r) {
                const int pos = mloc16 + quad * 4 + r + 1;
                float v = acc[jl][r];
                float partner = __shfl_xor(v, 1, 64);
                float ang = (float)pos * th;
                float rev = ang * 0.15915494309189535f;   // 1/(2*pi)
                rev -= floorf(rev);
                float sn = __builtin_amdgcn_sinf(rev);
                float cs = __builtin_amdgcn_cosf(rev);
                float res = (h & 1) ? (v * cs - partner * sn)
                                    : (v * cs + partner * sn);
                U16x8 u; u.bf[0] = (__bf16)res;
                T[(quad * 4 + r) * 136 + h] = u.us[0];
            }
        }
        // wave-private LDS: in-order DS ops, no barrier needed
        #pragma unroll
        for (int c4l = 0; c4l < 2; ++c4l) {
            const int c4 = jh * 2 + c4l;
            uint4 d = *(const uint4*)&T[(ln & 15) * 136 + c4 * 32 + (ln >> 4) * 8];
            *(uint4*)&dstP[(size_t)(t16 * 4 + c4) * 512 + ln * 8] = d;
        }
    } else {
        const int r2 = bx - 2048;
        const int jh = r2 >> 8;
        const int mt = r2 & 255;
        const int mt16 = mt * 2;

        const __bf16* WFp = WF + (size_t)2 * (32 * 8 * 512) + (size_t)jh * (4 * 512);
        const size_t xb0 = (size_t)mt16 * 32, xb1 = xb0 + 32;

        bfx8 xA[2], xB[2], wA[4], wB[4];
        xA[0] = *(const bfx8*)&xF[(xb0 + 0) * 512 + ln * 8];
        xA[1] = *(const bfx8*)&xF[(xb1 + 0) * 512 + ln * 8];
        xB[0] = *(const bfx8*)&xF[(xb0 + 1) * 512 + ln * 8];
        xB[1] = *(const bfx8*)&xF[(xb1 + 1) * 512 + ln * 8];
        #pragma unroll
        for (int jl = 0; jl < 4; ++jl) {
            wA[jl] = *(const bfx8*)&WFp[(size_t)jl * 512 + ln * 8];
            wB[jl] = *(const bfx8*)&WFp[(size_t)(8 + jl) * 512 + ln * 8];
        }

        f32x4 acc[2][4];
        #pragma unroll
        for (int iq = 0; iq < 2; ++iq)
            #pragma unroll
            for (int jl = 0; jl < 4; ++jl) acc[iq][jl] = (f32x4)(0.f);

        for (int kc = 0; kc < 32; kc += 2) {
            const int kpA = (kc + 2 < 32) ? kc + 2 : kc;
            #pragma unroll
            for (int jl = 0; jl < 4; ++jl) {
                acc[0][jl] = __builtin_amdgcn_mfma_f32_16x16x32_bf16(xA[0], wA[jl], acc[0][jl], 0, 0, 0);
                acc[1][jl] = __builtin_amdgcn_mfma_f32_16x16x32_bf16(xA[1], wA[jl], acc[1][jl], 0, 0, 0);
                wA[jl] = *(const bfx8*)&WFp[((size_t)kpA * 8 + jl) * 512 + ln * 8];
            }
            xA[0] = *(const bfx8*)&xF[(xb0 + kpA) * 512 + ln * 8];
            xA[1] = *(const bfx8*)&xF[(xb1 + kpA) * 512 + ln * 8];
            const int kpB = (kc + 3 < 32) ? kc + 3 : kc + 1;
            #pragma unroll
            for (int jl = 0; jl < 4; ++jl) {
                acc[0][jl] = __builtin_amdgcn_mfma_f32_16x16x32_bf16(xB[0], wB[jl], acc[0][jl], 0, 0, 0);
                acc[1][jl] = __builtin_amdgcn_mfma_f32_16x16x32_bf16(xB[1], wB[jl], acc[1][jl], 0, 0, 0);
                wB[jl] = *(const bfx8*)&WFp[((size_t)kpB * 8 + jl) * 512 + ln * 8];
            }
            xB[0] = *(const bfx8*)&xF[(xb0 + kpB) * 512 + ln * 8];
            xB[1] = *(const bfx8*)&xF[(xb1 + kpB) * 512 + ln * 8];
        }

        const int b = mt >> 6;
        const int kt32 = mt & 63;
        #pragma unroll
        for (int iq = 0; iq < 2; ++iq)
            #pragma unroll
            for (int jl = 0; jl < 4; ++jl) {
                const int j = jh * 4 + jl;
                #pragma unroll
                for (int r = 0; r < 4; ++r) {
                    U16x8 u; u.bf[0] = (__bf16)acc[iq][jl][r];
                    T[(iq * 16 + quad * 4 + r) * 136 + j * 16 + lo] = u.us[0];
                }
            }
        __bf16* dstP = VF + (size_t)b * FRAG_B;
        #pragma unroll
        for (int jl = 0; jl < 4; ++jl) {
            const int j = jh * 4 + jl;
            U16x8 u;
            #pragma unroll
            for (int e = 0; e < 8; ++e)
                u.us[e] = T[((ln >> 4) * 8 + e) * 136 + j * 16 + (ln & 15)];
            *(uint4*)&dstP[(size_t)(kt32 * 8 + j) * 512 + ln * 8] = u.u4;
        }
    }
}

// ---------------- Kernel B: attention partials + last-block merge -------------------
// grid (8, 32, 8): blockIdx.x = 2b + (qt&1) -> XCD-localized K/V (round-6 layout).
// Block body identical to round 6. After writing its Opb/Ll partial, each block does
// release-fence + atomicAdd on Cnt[b*64+qt]; the LAST finisher (old == nc-1) acquires
// and executes the exact round-6 merge for this (b,qt) — summation order cc=0..nc-1
// unchanged -> bit-identical output. Saves the 4th kernel launch + gap, and merges
// overlap the attn tail.
__global__ __launch_bounds__(128) void attn_partial_kernel(
    const __bf16* __restrict__ QF, const __bf16* __restrict__ KF,
    const __bf16* __restrict__ VF,
    __bf16* __restrict__ Opb, float* __restrict__ Ll,
    unsigned int* __restrict__ Cnt, float* __restrict__ out)
{
    const int bxx = blockIdx.x;            // 2b + (qt&1)
    const int b = bxx >> 1;
    const int qt = (int)blockIdx.y * 2 + (bxx & 1);
    const int c = blockIdx.z;
    const int qbase = qt * 32;
    const int kstart = c << 8;
    if (kstart > qbase) return;
    const int nt = min(8, (qbase + 32 - kstart) >> 5);
    const int ncq = (qt >> 3) + 1;         // chunks for this qt

    __shared__ __align__(16) unsigned short Pw[2][1280];   // per-wave P bounce, 5 KB
    __shared__ float RedO[2 * 8 * 4 * 64];                 // 16 KB (reused as Lsh)
    __shared__ float RedL[2 * 4 * 64];                     // 2 KB
    __shared__ int isLastSh;

    const int tid = threadIdx.x;
    const int w = tid >> 6;            // wave 0/1
    const int ln = tid & 63;
    const int lo = ln & 15, quad = ln >> 4;
    const int hi8 = quad * 8;

    const __bf16* QFb = QF + (size_t)b * FRAG_B;
    const __bf16* KFb = KF + (size_t)b * FRAG_B;
    const __bf16* VFb = VF + (size_t)b * FRAG_B;

    bfx8 qf[2][4];
    #pragma unroll
    for (int iq = 0; iq < 2; ++iq)
        #pragma unroll
        for (int c4 = 0; c4 < 4; ++c4)
            qf[iq][c4] = *(const bfx8*)&QFb[(size_t)((qt * 2 + iq) * 4 + c4) * 512 + ln * 8];

    f32x4 O[2][8];
    #pragma unroll
    for (int iq = 0; iq < 2; ++iq)
        #pragma unroll
        for (int j = 0; j < 8; ++j) O[iq][j] = (f32x4)(0.f);
    float lsum[2][4];
    #pragma unroll
    for (int iq = 0; iq < 2; ++iq)
        #pragma unroll
        for (int r = 0; r < 4; ++r) lsum[iq][r] = 0.f;

    bfx8 kcur[2][4], knxt[2][4];
    {
        const int kf0 = (kstart + w * 32) >> 4;
        #pragma unroll
        for (int jj = 0; jj < 2; ++jj)
            #pragma unroll
            for (int c4 = 0; c4 < 4; ++c4)
                kcur[jj][c4] = *(const bfx8*)&KFb[(size_t)((kf0 + jj) * 4 + c4) * 512 + ln * 8];
    }

    for (int kt = w; kt < nt; kt += 2) {
        const int k0 = kstart + kt * 32;
        bfx8 vf[8];
        #pragma unroll
        for (int j = 0; j < 8; ++j)
            vf[j] = *(const bfx8*)&VFb[(size_t)((k0 >> 5) * 8 + j) * 512 + ln * 8];
        if (kt + 2 < nt) {
            const int kn16 = (k0 + 64) >> 4;
            #pragma unroll
            for (int jj = 0; jj < 2; ++jj)
                #pragma unroll
                for (int c4 = 0; c4 < 4; ++c4)
                    knxt[jj][c4] = *(const bfx8*)&KFb[(size_t)((kn16 + jj) * 4 + c4) * 512 + ln * 8];
        }

        f32x4 s4[2][2];
        #pragma unroll
        for (int iq = 0; iq < 2; ++iq)
            #pragma unroll
            for (int jj = 0; jj < 2; ++jj) s4[iq][jj] = (f32x4)(0.f);
        #pragma unroll
        for (int c4 = 0; c4 < 4; ++c4)
            #pragma unroll
            for (int iq = 0; iq < 2; ++iq)
                #pragma unroll
                for (int jj = 0; jj < 2; ++jj)
                    s4[iq][jj] = __builtin_amdgcn_mfma_f32_16x16x32_bf16(qf[iq][c4], kcur[jj][c4], s4[iq][jj], 0, 0, 0);

        const bool needMask = (k0 + 31 > qbase);
        #pragma unroll
        for (int iq = 0; iq < 2; ++iq)
            #pragma unroll
            for (int jj = 0; jj < 2; ++jj)
                #pragma unroll
                for (int r = 0; r < 4; ++r) {
                    const int col = k0 + jj * 16 + lo;
                    const int row = qbase + iq * 16 + quad * 4 + r;
                    float p = __expf(s4[iq][jj][r] * 0.03125f);   // scale 1024^-0.5
                    if (needMask && col > row) p = 0.f;
                    lsum[iq][r] += p;
                    U16x8 u; u.bf[0] = (__bf16)p;
                    Pw[w][iq * 640 + (quad * 4 + r) * 40 + jj * 16 + lo] = u.us[0];
                }

        bfx8 pf0 = *(const bfx8*)&Pw[w][lo * 40 + hi8];
        bfx8 pf1 = *(const bfx8*)&Pw[w][640 + lo * 40 + hi8];
        #pragma unroll
        for (int j = 0; j < 8; ++j) {
            O[0][j] = __builtin_amdgcn_mfma_f32_16x16x32_bf16(pf0, vf[j], O[0][j], 0, 0, 0);
            O[1][j] = __builtin_amdgcn_mfma_f32_16x16x32_bf16(pf1, vf[j], O[1][j], 0, 0, 0);
        }

        #pragma unroll
        for (int jj = 0; jj < 2; ++jj)
            #pragma unroll
            for (int c4 = 0; c4 < 4; ++c4) kcur[jj][c4] = knxt[jj][c4];
    }

    // wave-local row reduce of lsum (within 16-lane groups)
    #pragma unroll
    for (int off = 1; off < 16; off <<= 1)
        #pragma unroll
        for (int iq = 0; iq < 2; ++iq)
            #pragma unroll
            for (int r = 0; r < 4; ++r) lsum[iq][r] += __shfl_xor(lsum[iq][r], off, 64);

    // cross-wave combine: exact (plain-exp partials are additive)
    if (w == 1) {
        #pragma unroll
        for (int iq = 0; iq < 2; ++iq)
            #pragma unroll
            for (int j = 0; j < 8; ++j)
                #pragma unroll
                for (int r = 0; r < 4; ++r)
                    RedO[((iq * 8 + j) * 4 + r) * 64 + ln] = O[iq][j][r];
        #pragma unroll
        for (int iq = 0; iq < 2; ++iq)
            #pragma unroll
            for (int r = 0; r < 4; ++r)
                RedL[(iq * 4 + r) * 64 + ln] = lsum[iq][r];
    }
    __syncthreads();
    if (w == 0) {
        #pragma unroll
        for (int iq = 0; iq < 2; ++iq)
            #pragma unroll
            for (int j = 0; j < 8; ++j)
                #pragma unroll
                for (int r = 0; r < 4; ++r)
                    O[iq][j][r] += RedO[((iq * 8 + j) * 4 + r) * 64 + ln];
        #pragma unroll
        for (int iq = 0; iq < 2; ++iq)
            #pragma unroll
            for (int r = 0; r < 4; ++r)
                lsum[iq][r] += RedL[(iq * 4 + r) * 64 + ln];

        const size_t sb = (size_t)b * SLOTS + slot_base32(qt) + c;
        #pragma unroll
        for (int iq = 0; iq < 2; ++iq)
            #pragma unroll
            for (int j = 0; j < 8; ++j) {
                U16x8 u;
                u.bf[0] = (__bf16)O[iq][j][0]; u.bf[1] = (__bf16)O[iq][j][1];
                u.bf[2] = (__bf16)O[iq][j][2]; u.bf[3] = (__bf16)O[iq][j][3];
                *(uint2*)&Opb[((sb * 2 + iq) * 8 + j) * 256 + ln * 4] = make_uint2(u.ui[0], u.ui[1]);
            }
        if (lo == 0) {
            #pragma unroll
            for (int iq = 0; iq < 2; ++iq)
                #pragma unroll
                for (int r = 0; r < 4; ++r)
                    Ll[sb * 32 + iq * 16 + quad * 4 + r] = lsum[iq][r];
        }
    }

    // ---- completion protocol: release, count, last block merges --------------------
    __syncthreads();                        // all partial stores issued (w0 wave)
    if (tid == 0) {
        __threadfence();                    // release: Opb/Ll visible device-wide
        unsigned int old = atomicAdd(&Cnt[b * 64 + qt], 1u);
        isLastSh = (old == (unsigned int)(ncq - 1)) ? 1 : 0;
    }
    __syncthreads();
    if (!isLastSh) return;
    __threadfence();                        // acquire: other blocks' partials visible

    // ---- merge (exact round-6 body; 128 threads, jh2 looped) -----------------------
    {
        const size_t base = (size_t)b * SLOTS + slot_base32(qt);
        float* Lsh = RedO;                  // reuse 16 KB buffer; need ncq*32 <= 256
        for (int idx = tid; idx < ncq * 32; idx += 128)
            Lsh[idx] = Ll[(base + (idx >> 5)) * 32 + (idx & 31)];
        __syncthreads();

        const int iqm = tid >> 6;           // 0/1
        const int l2 = tid & 63;
        const int lo2 = l2 & 15, q2 = l2 >> 4;

        #pragma unroll
        for (int jh2 = 0; jh2 < 2; ++jh2) {
            float accm[4][4];
            #pragma unroll
            for (int jl = 0; jl < 4; ++jl)
                #pragma unroll
                for (int r = 0; r < 4; ++r) accm[jl][r] = 0.f;

            for (int cc = 0; cc < ncq; ++cc) {
                #pragma unroll
                for (int jl = 0; jl < 4; ++jl) {
                    const int j = jh2 * 4 + jl;
                    uint2 d = *(const uint2*)&Opb[(((base + cc) * 2 + iqm) * 8 + j) * 256 + l2 * 4];
                    U16x8 u; u.ui[0] = d.x; u.ui[1] = d.y;
                    #pragma unroll
                    for (int r = 0; r < 4; ++r) accm[jl][r] += (float)u.bf[r];
                }
            }

            #pragma unroll
            for (int r = 0; r < 4; ++r) {
                const int row = iqm * 16 + q2 * 4 + r;
                float l = 0.f;
                for (int cc = 0; cc < ncq; ++cc) l += Lsh[cc * 32 + row];
                const float rl = 1.0f / l;
                #pragma unroll
                for (int jl = 0; jl < 4; ++jl) {
                    const int j = jh2 * 4 + jl;
                    out[((size_t)b * T_SEQ + qt * 32 + row) * DH + j * 16 + lo2] = accm[jl][r] * rl;
                }
            }
        }
    }
}

extern "C" void kernel_launch(void* const* d_in, const int* in_sizes, int n_in,
                              void* d_out, int out_size, void* d_ws, size_t ws_size,
                              hipStream_t stream) {
    const float* x     = (const float*)d_in[0];
    const float* Wq    = (const float*)d_in[1];
    const float* Wk    = (const float*)d_in[2];
    const float* Wv    = (const float*)d_in[3];
    const float* theta = (const float*)d_in[4];
    float* out = (float*)d_out;

    const int M = in_sizes[0] / D_MODEL;   // B*T = 8192
    const int B = M / T_SEQ;               // 4

    // ws: xF 16.8 MB | WF 0.75 | QF/KF/VF 2.1 each | Opb 9.4 | Ll 0.15 | Cnt 1KB
    __bf16* xF  = (__bf16*)d_ws;                     // M*1024 bf16
    __bf16* WF  = xF + (size_t)M * D_MODEL;          // 3*32*8*512
    __bf16* QF  = WF + (size_t)3 * 32 * 8 * 512;
    __bf16* KF  = QF + (size_t)B * FRAG_B;
    __bf16* VF  = KF + (size_t)B * FRAG_B;
    __bf16* Opb = VF + (size_t)B * FRAG_B;
    float*  Ll  = (float*)(Opb + (size_t)B * SLOTS * 2 * 8 * 256);
    unsigned int* Cnt = (unsigned int*)(Ll + (size_t)B * SLOTS * 32);

    const int nxb = (M / 64) * 16;                   // 2048 xcvt blocks
    prep_kernel<<<dim3(nxb + 192), 256, 0, stream>>>(x, Wq, Wk, Wv, xF, WF, Cnt, nxb);
    qkv_kernel<<<dim3(2048 + 512), 64, 0, stream>>>(xF, WF, theta, QF, KF, VF);
    attn_partial_kernel<<<dim3(2 * B, T_SEQ / 64, 8), 128, 0, stream>>>(QF, KF, VF, Opb, Ll, Cnt, out);
}

// Round 11
// 121.779 us; speedup vs baseline: 2.9925x; 1.4035x over previous
//
#include <hip/hip_runtime.h>
#include <math.h>

#define T_SEQ 2048
#define D_MODEL 1024
#define DH 128
#define SLOTS 288          // per batch: sum_{qt=0..63} ((qt>>3)+1)
#define FRAG_B 262144      // frag-plane elems per batch: 128*4*512 (= 64*8*512)

typedef __bf16 bfx8 __attribute__((ext_vector_type(8)));
typedef float f32x4 __attribute__((ext_vector_type(4)));

union U16x8 { uint4 u4; unsigned int ui[4]; unsigned short us[8]; __bf16 bf[8]; bfx8 v; };

__device__ inline uint4 cvt8u(float4 a, float4 b) {
    U16x8 u;
    u.bf[0] = (__bf16)a.x; u.bf[1] = (__bf16)a.y; u.bf[2] = (__bf16)a.z; u.bf[3] = (__bf16)a.w;
    u.bf[4] = (__bf16)b.x; u.bf[5] = (__bf16)b.y; u.bf[6] = (__bf16)b.z; u.bf[7] = (__bf16)b.w;
    return u.u4;
}

__device__ inline int slot_base32(int qt) {   // sum_{i<qt} ((i>>3)+1)
    int g = qt >> 3, j = qt & 7;
    return 4 * g * (g + 1) + j * (g + 1);
}

// ---------------- Kernel P: prep — x -> xF (A-frag order), W -> WF (B-frag order) ----
// blocks [0, nxb): xcvt. 64m x 64k tile via LDS transpose-to-frag; coalesced in/out.
// blocks [nxb, nxb+192): wcvt. One-pass gather of 1.5 MB W into B-frag order.
// xF frag id = mt16*32 + kc : lane ln -> x[mt16*16 + (ln&15)][kc*32 + (ln>>4)*8 + e]
// WF frag id = (wsel*32 + kc)*8 + j : lane ln -> W[j*16+(ln&15)][kc*32+(ln>>4)*8+e]
__global__ __launch_bounds__(256) void prep_kernel(
    const float* __restrict__ x,
    const float* __restrict__ Wq, const float* __restrict__ Wk,
    const float* __restrict__ Wv,
    __bf16* __restrict__ xF, __bf16* __restrict__ WF, int nxb)
{
    const int bi = blockIdx.x;
    const int tid = threadIdx.x;

    if (bi < nxb) {
        __shared__ __align__(16) unsigned short Xs[64 * 72];   // 9 KB
        const int m0 = (bi >> 4) * 64;
        const int k0 = (bi & 15) * 64;
        const int row = tid >> 2, cs = (tid & 3) * 16;
        const float* xp = x + (size_t)(m0 + row) * D_MODEL + k0 + cs;
        float4 a0 = *(const float4*)xp;
        float4 a1 = *(const float4*)(xp + 4);
        float4 a2 = *(const float4*)(xp + 8);
        float4 a3 = *(const float4*)(xp + 12);
        *(uint4*)&Xs[row * 72 + cs]     = cvt8u(a0, a1);
        *(uint4*)&Xs[row * 72 + cs + 8] = cvt8u(a2, a3);
        __syncthreads();
        const int L = tid & 63;
        #pragma unroll
        for (int rr = 0; rr < 2; ++rr) {
            const int fid = rr * 4 + (tid >> 6);   // 8 local frags: mtl(4) x kcl(2)
            const int mtl = fid >> 1, kcl = fid & 1;
            uint4 d = *(const uint4*)&Xs[(mtl * 16 + (L & 15)) * 72 + kcl * 32 + (L >> 4) * 8];
            const size_t frag = (size_t)((m0 >> 4) + mtl) * 32 + (k0 >> 5) + kcl;
            *(uint4*)&xF[frag * 512 + L * 8] = d;
        }
    } else {
        const int i = (bi - nxb) * 256 + tid;      // 49152 threads
        const int wsel = i >> 14;
        const int i2 = i & 16383;
        const int kc = i2 >> 9, j = (i2 >> 6) & 7, ln = i2 & 63;
        const int lo = ln & 15, quad = ln >> 4;
        const float* src = (wsel == 0) ? Wq : (wsel == 1) ? Wk : Wv;
        const float* p = src + (size_t)(j * 16 + lo) * D_MODEL + kc * 32 + quad * 8;
        float4 a = *(const float4*)p;
        float4 b = *(const float4*)(p + 4);
        *(uint4*)&WF[(size_t)((wsel * 32 + kc) * 8 + j) * 512 + ln * 8] = cvt8u(a, b);
    }
}

// ---------------- Kernel A: QKV — fine-split wave GEMM + RoPE (round-4 geometry) ----
// 2560 single-wave blocks (10/CU = 2.5 waves/SIMD) — measured optimum of this family:
//   bx in [0,2048): Q/K wave = (wsel01, iq, jh, mt): 16 m-rows x 4 j-frags x K=32.
//   bx in [2048,2560): V wave = (jh, mt): 32 m-rows x 4 j-frags x K=32.
// mt in LOW bits of bx -> consecutive blocks round-robin XCDs; xF slab L2-hot.
// Depth-2 ping-pong prefetch, reload-in-place after last consumer.
__global__ __launch_bounds__(64) void qkv_kernel(
    const __bf16* __restrict__ xF, const __bf16* __restrict__ WF,
    const float* __restrict__ theta,
    __bf16* __restrict__ QF, __bf16* __restrict__ KF, __bf16* __restrict__ VF)
{
    __shared__ __align__(16) unsigned short T[32 * 136];   // 8.7 KB wave-private

    const int bx = blockIdx.x;
    const int ln = threadIdx.x;
    const int lo = ln & 15, quad = ln >> 4;

    if (bx < 2048) {
        // ---------------- Q/K wave: 16 rows (iq half), 4 j-frags (jh half) ----------
        const int wsel01 = bx >> 10;           // 0=Q, 1=K
        const int sub = (bx >> 8) & 3;
        const int iq = sub >> 1, jh = sub & 1;
        const int mt = bx & 255;
        const int mt16 = mt * 2 + iq;          // global 16-row granule

        const __bf16* WFp = WF + (size_t)wsel01 * (32 * 8 * 512) + (size_t)jh * (4 * 512);
        const size_t xb = (size_t)mt16 * 32;

        bfx8 xA = *(const bfx8*)&xF[(xb + 0) * 512 + ln * 8];
        bfx8 xB = *(const bfx8*)&xF[(xb + 1) * 512 + ln * 8];
        bfx8 wA[4], wB[4];
        #pragma unroll
        for (int jl = 0; jl < 4; ++jl) {
            wA[jl] = *(const bfx8*)&WFp[(size_t)jl * 512 + ln * 8];
            wB[jl] = *(const bfx8*)&WFp[(size_t)(8 + jl) * 512 + ln * 8];
        }

        f32x4 acc[4];
        #pragma unroll
        for (int jl = 0; jl < 4; ++jl) acc[jl] = (f32x4)(0.f);

        for (int kc = 0; kc < 32; kc += 2) {
            const int kpA = (kc + 2 < 32) ? kc + 2 : kc;   // tail clamp: harmless reload
            #pragma unroll
            for (int jl = 0; jl < 4; ++jl) {
                acc[jl] = __builtin_amdgcn_mfma_f32_16x16x32_bf16(xA, wA[jl], acc[jl], 0, 0, 0);
                wA[jl] = *(const bfx8*)&WFp[((size_t)kpA * 8 + jl) * 512 + ln * 8];
            }
            xA = *(const bfx8*)&xF[(xb + kpA) * 512 + ln * 8];
            const int kpB = (kc + 3 < 32) ? kc + 3 : kc + 1;
            #pragma unroll
            for (int jl = 0; jl < 4; ++jl) {
                acc[jl] = __builtin_amdgcn_mfma_f32_16x16x32_bf16(xB, wB[jl], acc[jl], 0, 0, 0);
                wB[jl] = *(const bfx8*)&WFp[((size_t)kpB * 8 + jl) * 512 + ln * 8];
            }
            xB = *(const bfx8*)&xF[(xb + kpB) * 512 + ln * 8];
        }

        // ---- epilogue: RoPE + T-bounce, restricted to this wave's (iq, jh) slice ----
        const int b = mt16 >> 7;
        const int t16 = mt16 & 127;
        const int mloc16 = t16 * 16;
        __bf16* dstP = (wsel01 == 0 ? QF : KF) + (size_t)b * FRAG_B;

        #pragma unroll
        for (int jl = 0; jl < 4; ++jl) {
            const int j = jh * 4 + jl;
            const int h = j * 16 + lo;
            const float th = theta[h];
            #pragma unroll
            for (int r = 0; r < 4; ++r) {
                const int pos = mloc16 + quad * 4 + r + 1;
                float v = acc[jl][r];
                float partner = __shfl_xor(v, 1, 64);
                float ang = (float)pos * th;
                float rev = ang * 0.15915494309189535f;   // 1/(2*pi)
                rev -= floorf(rev);
                float sn = __builtin_amdgcn_sinf(rev);
                float cs = __builtin_amdgcn_cosf(rev);
                float res = (h & 1) ? (v * cs - partner * sn)
                                    : (v * cs + partner * sn);
                U16x8 u; u.bf[0] = (__bf16)res;
                T[(quad * 4 + r) * 136 + h] = u.us[0];
            }
        }
        // wave-private LDS: in-order DS ops, no barrier needed
        #pragma unroll
        for (int c4l = 0; c4l < 2; ++c4l) {
            const int c4 = jh * 2 + c4l;
            uint4 d = *(const uint4*)&T[(ln & 15) * 136 + c4 * 32 + (ln >> 4) * 8];
            *(uint4*)&dstP[(size_t)(t16 * 4 + c4) * 512 + ln * 8] = d;
        }
    } else {
        // ---------------- V wave: 32 rows, 4 j-frags (jh half) ----------------------
        const int r2 = bx - 2048;
        const int jh = r2 >> 8;
        const int mt = r2 & 255;
        const int mt16 = mt * 2;

        const __bf16* WFp = WF + (size_t)2 * (32 * 8 * 512) + (size_t)jh * (4 * 512);
        const size_t xb0 = (size_t)mt16 * 32, xb1 = xb0 + 32;

        bfx8 xA[2], xB[2], wA[4], wB[4];
        xA[0] = *(const bfx8*)&xF[(xb0 + 0) * 512 + ln * 8];
        xA[1] = *(const bfx8*)&xF[(xb1 + 0) * 512 + ln * 8];
        xB[0] = *(const bfx8*)&xF[(xb0 + 1) * 512 + ln * 8];
        xB[1] = *(const bfx8*)&xF[(xb1 + 1) * 512 + ln * 8];
        #pragma unroll
        for (int jl = 0; jl < 4; ++jl) {
            wA[jl] = *(const bfx8*)&WFp[(size_t)jl * 512 + ln * 8];
            wB[jl] = *(const bfx8*)&WFp[(size_t)(8 + jl) * 512 + ln * 8];
        }

        f32x4 acc[2][4];
        #pragma unroll
        for (int iq = 0; iq < 2; ++iq)
            #pragma unroll
            for (int jl = 0; jl < 4; ++jl) acc[iq][jl] = (f32x4)(0.f);

        for (int kc = 0; kc < 32; kc += 2) {
            const int kpA = (kc + 2 < 32) ? kc + 2 : kc;
            #pragma unroll
            for (int jl = 0; jl < 4; ++jl) {
                acc[0][jl] = __builtin_amdgcn_mfma_f32_16x16x32_bf16(xA[0], wA[jl], acc[0][jl], 0, 0, 0);
                acc[1][jl] = __builtin_amdgcn_mfma_f32_16x16x32_bf16(xA[1], wA[jl], acc[1][jl], 0, 0, 0);
                wA[jl] = *(const bfx8*)&WFp[((size_t)kpA * 8 + jl) * 512 + ln * 8];
            }
            xA[0] = *(const bfx8*)&xF[(xb0 + kpA) * 512 + ln * 8];
            xA[1] = *(const bfx8*)&xF[(xb1 + kpA) * 512 + ln * 8];
            const int kpB = (kc + 3 < 32) ? kc + 3 : kc + 1;
            #pragma unroll
            for (int jl = 0; jl < 4; ++jl) {
                acc[0][jl] = __builtin_amdgcn_mfma_f32_16x16x32_bf16(xB[0], wB[jl], acc[0][jl], 0, 0, 0);
                acc[1][jl] = __builtin_amdgcn_mfma_f32_16x16x32_bf16(xB[1], wB[jl], acc[1][jl], 0, 0, 0);
                wB[jl] = *(const bfx8*)&WFp[((size_t)kpB * 8 + jl) * 512 + ln * 8];
            }
            xB[0] = *(const bfx8*)&xF[(xb0 + kpB) * 512 + ln * 8];
            xB[1] = *(const bfx8*)&xF[(xb1 + kpB) * 512 + ln * 8];
        }

        // ---- epilogue: C (col lo=d, row quad*4+r=t) -> B-frag [t=quad*8+e][d=lo] ----
        const int b = mt >> 6;
        const int kt32 = mt & 63;
        #pragma unroll
        for (int iq = 0; iq < 2; ++iq)
            #pragma unroll
            for (int jl = 0; jl < 4; ++jl) {
                const int j = jh * 4 + jl;
                #pragma unroll
                for (int r = 0; r < 4; ++r) {
                    U16x8 u; u.bf[0] = (__bf16)acc[iq][jl][r];
                    T[(iq * 16 + quad * 4 + r) * 136 + j * 16 + lo] = u.us[0];
                }
            }
        __bf16* dstP = VF + (size_t)b * FRAG_B;
        #pragma unroll
        for (int jl = 0; jl < 4; ++jl) {
            const int j = jh * 4 + jl;
            U16x8 u;
            #pragma unroll
            for (int e = 0; e < 8; ++e)
                u.us[e] = T[((ln >> 4) * 8 + e) * 136 + j * 16 + (ln & 15)];
            *(uint4*)&dstP[(size_t)(kt32 * 8 + j) * 512 + ln * 8] = u.u4;
        }
    }
}

// ---------------- Kernel B: attention partials — XCD-localized, 2 waves per chunk ---
// grid (8, 32, 8): blockIdx.x = 2b + (qt&1) -> XCD = linear%8 = 2b+(qt&1).
// Each XCD serves ONE batch / one qt-parity: per-XCD K/V working set = 4.2 MB (~L2)
// instead of ~25 MB (all batches) -> K/V frag loads become L2 hits. Tile counts per
// XCD are exactly balanced. Block body identical to round 4.
__global__ __launch_bounds__(128) void attn_partial_kernel(
    const __bf16* __restrict__ QF, const __bf16* __restrict__ KF,
    const __bf16* __restrict__ VF,
    __bf16* __restrict__ Opb, float* __restrict__ Ll)
{
    const int bxx = blockIdx.x;            // 2b + (qt&1)
    const int b = bxx >> 1;
    const int qt = (int)blockIdx.y * 2 + (bxx & 1);
    const int c = blockIdx.z;
    const int qbase = qt * 32;
    const int kstart = c << 8;
    if (kstart > qbase) return;
    const int nt = min(8, (qbase + 32 - kstart) >> 5);

    __shared__ __align__(16) unsigned short Pw[2][1280];   // per-wave P bounce, 5 KB
    __shared__ float RedO[2 * 8 * 4 * 64];                 // 16 KB: [iq][j][r][lane]
    __shared__ float RedL[2 * 4 * 64];                     // 2 KB:  [iq][r][lane]

    const int tid = threadIdx.x;
    const int w = tid >> 6;            // wave 0/1
    const int ln = tid & 63;
    const int lo = ln & 15, quad = ln >> 4;
    const int hi8 = quad * 8;

    const __bf16* QFb = QF + (size_t)b * FRAG_B;
    const __bf16* KFb = KF + (size_t)b * FRAG_B;
    const __bf16* VFb = VF + (size_t)b * FRAG_B;

    bfx8 qf[2][4];
    #pragma unroll
    for (int iq = 0; iq < 2; ++iq)
        #pragma unroll
        for (int c4 = 0; c4 < 4; ++c4)
            qf[iq][c4] = *(const bfx8*)&QFb[(size_t)((qt * 2 + iq) * 4 + c4) * 512 + ln * 8];

    f32x4 O[2][8];
    #pragma unroll
    for (int iq = 0; iq < 2; ++iq)
        #pragma unroll
        for (int j = 0; j < 8; ++j) O[iq][j] = (f32x4)(0.f);
    float lsum[2][4];
    #pragma unroll
    for (int iq = 0; iq < 2; ++iq)
        #pragma unroll
        for (int r = 0; r < 4; ++r) lsum[iq][r] = 0.f;

    // prologue: wave w's first tile (kstart + w*32; in-bounds even if nt <= w)
    bfx8 kcur[2][4], knxt[2][4];
    {
        const int kf0 = (kstart + w * 32) >> 4;
        #pragma unroll
        for (int jj = 0; jj < 2; ++jj)
            #pragma unroll
            for (int c4 = 0; c4 < 4; ++c4)
                kcur[jj][c4] = *(const bfx8*)&KFb[(size_t)((kf0 + jj) * 4 + c4) * 512 + ln * 8];
    }

    for (int kt = w; kt < nt; kt += 2) {
        const int k0 = kstart + kt * 32;
        bfx8 vf[8];
        #pragma unroll
        for (int j = 0; j < 8; ++j)
            vf[j] = *(const bfx8*)&VFb[(size_t)((k0 >> 5) * 8 + j) * 512 + ln * 8];
        if (kt + 2 < nt) {
            const int kn16 = (k0 + 64) >> 4;
            #pragma unroll
            for (int jj = 0; jj < 2; ++jj)
                #pragma unroll
                for (int c4 = 0; c4 < 4; ++c4)
                    knxt[jj][c4] = *(const bfx8*)&KFb[(size_t)((kn16 + jj) * 4 + c4) * 512 + ln * 8];
        }

        f32x4 s4[2][2];
        #pragma unroll
        for (int iq = 0; iq < 2; ++iq)
            #pragma unroll
            for (int jj = 0; jj < 2; ++jj) s4[iq][jj] = (f32x4)(0.f);
        #pragma unroll
        for (int c4 = 0; c4 < 4; ++c4)
            #pragma unroll
            for (int iq = 0; iq < 2; ++iq)
                #pragma unroll
                for (int jj = 0; jj < 2; ++jj)
                    s4[iq][jj] = __builtin_amdgcn_mfma_f32_16x16x32_bf16(qf[iq][c4], kcur[jj][c4], s4[iq][jj], 0, 0, 0);

        const bool needMask = (k0 + 31 > qbase);
        #pragma unroll
        for (int iq = 0; iq < 2; ++iq)
            #pragma unroll
            for (int jj = 0; jj < 2; ++jj)
                #pragma unroll
                for (int r = 0; r < 4; ++r) {
                    const int col = k0 + jj * 16 + lo;
                    const int row = qbase + iq * 16 + quad * 4 + r;
                    float p = __expf(s4[iq][jj][r] * 0.03125f);   // scale 1024^-0.5
                    if (needMask && col > row) p = 0.f;
                    lsum[iq][r] += p;
                    U16x8 u; u.bf[0] = (__bf16)p;
                    Pw[w][iq * 640 + (quad * 4 + r) * 40 + jj * 16 + lo] = u.us[0];
                }

        bfx8 pf0 = *(const bfx8*)&Pw[w][lo * 40 + hi8];
        bfx8 pf1 = *(const bfx8*)&Pw[w][640 + lo * 40 + hi8];
        #pragma unroll
        for (int j = 0; j < 8; ++j) {
            O[0][j] = __builtin_amdgcn_mfma_f32_16x16x32_bf16(pf0, vf[j], O[0][j], 0, 0, 0);
            O[1][j] = __builtin_amdgcn_mfma_f32_16x16x32_bf16(pf1, vf[j], O[1][j], 0, 0, 0);
        }

        #pragma unroll
        for (int jj = 0; jj < 2; ++jj)
            #pragma unroll
            for (int c4 = 0; c4 < 4; ++c4) kcur[jj][c4] = knxt[jj][c4];
    }

    // wave-local row reduce of lsum (within 16-lane groups)
    #pragma unroll
    for (int off = 1; off < 16; off <<= 1)
        #pragma unroll
        for (int iq = 0; iq < 2; ++iq)
            #pragma unroll
            for (int r = 0; r < 4; ++r) lsum[iq][r] += __shfl_xor(lsum[iq][r], off, 64);

    // cross-wave combine: exact (plain-exp partials are additive)
    if (w == 1) {
        #pragma unroll
        for (int iq = 0; iq < 2; ++iq)
            #pragma unroll
            for (int j = 0; j < 8; ++j)
                #pragma unroll
                for (int r = 0; r < 4; ++r)
                    RedO[((iq * 8 + j) * 4 + r) * 64 + ln] = O[iq][j][r];
        #pragma unroll
        for (int iq = 0; iq < 2; ++iq)
            #pragma unroll
            for (int r = 0; r < 4; ++r)
                RedL[(iq * 4 + r) * 64 + ln] = lsum[iq][r];
    }
    __syncthreads();
    if (w == 0) {
        #pragma unroll
        for (int iq = 0; iq < 2; ++iq)
            #pragma unroll
            for (int j = 0; j < 8; ++j)
                #pragma unroll
                for (int r = 0; r < 4; ++r)
                    O[iq][j][r] += RedO[((iq * 8 + j) * 4 + r) * 64 + ln];
        #pragma unroll
        for (int iq = 0; iq < 2; ++iq)
            #pragma unroll
            for (int r = 0; r < 4; ++r)
                lsum[iq][r] += RedL[(iq * 4 + r) * 64 + ln];

        const size_t sb = (size_t)b * SLOTS + slot_base32(qt) + c;
        #pragma unroll
        for (int iq = 0; iq < 2; ++iq)
            #pragma unroll
            for (int j = 0; j < 8; ++j) {
                U16x8 u;
                u.bf[0] = (__bf16)O[iq][j][0]; u.bf[1] = (__bf16)O[iq][j][1];
                u.bf[2] = (__bf16)O[iq][j][2]; u.bf[3] = (__bf16)O[iq][j][3];
                *(uint2*)&Opb[((sb * 2 + iq) * 8 + j) * 256 + ln * 4] = make_uint2(u.ui[0], u.ui[1]);
            }
        if (lo == 0) {
            #pragma unroll
            for (int iq = 0; iq < 2; ++iq)
                #pragma unroll
                for (int r = 0; r < 4; ++r)
                    Ll[sb * 32 + iq * 16 + quad * 4 + r] = lsum[iq][r];
        }
    }
}

// ---------------- Kernel C: merge partials (j folded x4: ILP over tiny blocks) ------
// grid (64 qt, B, 2): each block handles 4 j-planes; per lane 4*nc independent loads.
__global__ __launch_bounds__(128) void attn_merge_kernel(
    const __bf16* __restrict__ Opb, const float* __restrict__ Ll,
    float* __restrict__ out)
{
    const int qt = blockIdx.x, b = blockIdx.y, jh2 = blockIdx.z;
    const int g = qt >> 3, nc = g + 1;
    const size_t base = (size_t)b * SLOTS + slot_base32(qt);

    __shared__ float Lsh[8][32];
    const int tid = threadIdx.x;
    const int iq = tid >> 6, ln = tid & 63;
    const int lo = ln & 15, quad = ln >> 4;

    for (int idx = tid; idx < nc * 32; idx += 128)
        Lsh[idx >> 5][idx & 31] = Ll[(base + (idx >> 5)) * 32 + (idx & 31)];
    __syncthreads();

    float acc[4][4];
    #pragma unroll
    for (int jl = 0; jl < 4; ++jl)
        #pragma unroll
        for (int r = 0; r < 4; ++r) acc[jl][r] = 0.f;

    for (int cc = 0; cc < nc; ++cc) {
        #pragma unroll
        for (int jl = 0; jl < 4; ++jl) {
            const int j = jh2 * 4 + jl;
            uint2 d = *(const uint2*)&Opb[(((base + cc) * 2 + iq) * 8 + j) * 256 + ln * 4];
            U16x8 u; u.ui[0] = d.x; u.ui[1] = d.y;
            #pragma unroll
            for (int r = 0; r < 4; ++r) acc[jl][r] += (float)u.bf[r];
        }
    }

    #pragma unroll
    for (int r = 0; r < 4; ++r) {
        const int row = iq * 16 + quad * 4 + r;
        float l = 0.f;
        for (int cc = 0; cc < nc; ++cc) l += Lsh[cc][row];
        const float rl = 1.0f / l;
        #pragma unroll
        for (int jl = 0; jl < 4; ++jl) {
            const int j = jh2 * 4 + jl;
            out[((size_t)b * T_SEQ + qt * 32 + row) * DH + j * 16 + lo] = acc[jl][r] * rl;
        }
    }
}

extern "C" void kernel_launch(void* const* d_in, const int* in_sizes, int n_in,
                              void* d_out, int out_size, void* d_ws, size_t ws_size,
                              hipStream_t stream) {
    const float* x     = (const float*)d_in[0];
    const float* Wq    = (const float*)d_in[1];
    const float* Wk    = (const float*)d_in[2];
    const float* Wv    = (const float*)d_in[3];
    const float* theta = (const float*)d_in[4];
    float* out = (float*)d_out;

    const int M = in_sizes[0] / D_MODEL;   // B*T = 8192
    const int B = M / T_SEQ;               // 4

    // ws: xF 16.8 MB | WF 0.75 | QF/KF/VF 2.1 each | Opb 9.4 | Ll
    __bf16* xF  = (__bf16*)d_ws;                     // M*1024 bf16
    __bf16* WF  = xF + (size_t)M * D_MODEL;          // 3*32*8*512
    __bf16* QF  = WF + (size_t)3 * 32 * 8 * 512;
    __bf16* KF  = QF + (size_t)B * FRAG_B;
    __bf16* VF  = KF + (size_t)B * FRAG_B;
    __bf16* Opb = VF + (size_t)B * FRAG_B;
    float*  Ll  = (float*)(Opb + (size_t)B * SLOTS * 2 * 8 * 256);

    const int nxb = (M / 64) * 16;                   // 2048 xcvt blocks
    prep_kernel<<<dim3(nxb + 192), 256, 0, stream>>>(x, Wq, Wk, Wv, xF, WF, nxb);
    // Q/K: 2*(M/32)*4 = 2048 blocks; V: (M/32)*2 = 512 blocks  (round-4 geometry)
    qkv_kernel<<<dim3(2048 + 512), 64, 0, stream>>>(xF, WF, theta, QF, KF, VF);
    // XCD-localized grid: x = 2b+(qt&1), y = qt>>1, z = c
    attn_partial_kernel<<<dim3(2 * B, T_SEQ / 64, 8), 128, 0, stream>>>(QF, KF, VF, Opb, Ll);
    attn_merge_kernel<<<dim3(T_SEQ / 32, B, 2), 128, 0, stream>>>(Opb, Ll, out);
}